// Round 14
// baseline (2393.303 us; speedup 1.0000x reference)
//
#include <hip/hip_runtime.h>

#define Bb 64
#define Tt 512
#define Dd 256
#define Hh 1024
#define G3 3072

// workspace: self-validating h exchange, [2][4][8][4][64][8] u32 = 512 KB.
// u32 = hi16 | ((lo16 & ~3 | tag2) << 16); tag2 = (step+1)&3.
#define HF_BYTES (512*1024)
#define PLANE_U32 65536
#define PLANE_U64 32768

typedef __attribute__((ext_vector_type(8))) __bf16 bf16x8;
typedef __attribute__((ext_vector_type(4))) float f32x4;
typedef __attribute__((ext_vector_type(4))) unsigned int u32x4;

static __device__ __forceinline__ f32x4 mfma16(bf16x8 a, bf16x8 b, f32x4 c){
    return __builtin_amdgcn_mfma_f32_16x16x32_bf16(a, b, c, 0, 0, 0);
}
static __device__ __forceinline__ unsigned short bfbits(__bf16 v){
    return __builtin_bit_cast(unsigned short, v);
}

// u32 index of element (plane p, group m, col c, group-row row) in hF
static __device__ __forceinline__ size_t hfIdx(int p, int m, int c, int row){
    int e = c >> 7, ks = (c >> 5) & 3, kg = (c >> 3) & 3, i = c & 7;
    int lane = kg*16 + row;
    return (size_t)((((p*4 + m)*8 + e)*4 + ks)*64 + lane)*8 + i;
}

// gather embedding rows for timestep t into LDS x-buffer (hi/lo bf16 split),
// swizzled to match the MFMA A-fragment ds_read pattern. 256 threads
// (waves 4-7, lt 0..255), 4 chunks/thread. (r13 verbatim — verified passing)
__device__ __forceinline__ void gatherX256(__bf16* sxh, __bf16* sxl,
                                           const int* inp, const float* emb,
                                           int m, int t, int lt)
{
    int row = lt >> 4, c16 = lt & 15;
    int grow = m*16 + row;
    int tok = inp[grow*Tt + t];
    const float* er = emb + (long)tok * Dd;
    int swz = (row & 7) << 4;
    #pragma unroll
    for (int qq = 0; qq < 4; ++qq){
        int c = c16 + qq*16;                     // 4-float chunk, 0..63
        float4 v = *(const float4*)(er + c*4);
        int boff = row*512 + ((c*8) ^ swz);      // byte offset, 8B-aligned
        float vv[4] = {v.x, v.y, v.z, v.w};
        unsigned long long Hp = 0, Lp = 0;
        #pragma unroll
        for (int ee = 0; ee < 4; ++ee){
            __bf16 hb = (__bf16)vv[ee];
            __bf16 lb = (__bf16)(vv[ee] - (float)hb);
            Hp |= (unsigned long long)bfbits(hb) << (16*ee);
            Lp |= (unsigned long long)bfbits(lb) << (16*ee);
        }
        *(unsigned long long*)((char*)sxh + boff) = Hp;
        *(unsigned long long*)((char*)sxl + boff) = Lp;
    }
}

extern "C" __global__ void __launch_bounds__(512, 2)
gru_persist(const int* __restrict__ inp, const float* __restrict__ hid,
            const float* __restrict__ emb, const float* __restrict__ kern,
            const float* __restrict__ reck, const float* __restrict__ bias,
            float* __restrict__ out, unsigned char* __restrict__ ws)
{
    __shared__ __bf16 sX[2][2][16*256];  // [buf][hi/lo], 32 KB total (r2 layout)
    __shared__ float  sTile[8][4][256];  // [kwave][z,r,hrec,hx][row*16+col], 32 KB

    const int tid  = threadIdx.x;
    const int wid  = tid >> 6;
    const int lane = tid & 63;
    const int blk  = blockIdx.x;
    const int m = blk & 3;       // row group: rows 16m..16m+15
    const int n = blk >> 2;      // j group:  j = 16n..16n+15

    unsigned int* hF = (unsigned int*)ws;

    const int e    = wid;               // K-eighth owned by this wave (0..7)
    const int kgrp = lane >> 4;         // 0..3 (k sub-block)
    const int arow = lane & 15;         // A row / B col within tile

    // ---- one-time weight fragments in VGPRs (hi/lo bf16 split, r5 verbatim) ----
    bf16x8 Bh[3][4], Bl[3][4], XBh[3], XBl[3];
    #pragma unroll
    for (int g = 0; g < 3; ++g){
        #pragma unroll
        for (int ks = 0; ks < 4; ++ks){
            bf16x8 bh, bl;
            #pragma unroll
            for (int i = 0; i < 8; ++i){
                int k = e*128 + ks*32 + kgrp*8 + i;
                float f = reck[k*G3 + g*1024 + n*16 + arow];
                __bf16 h = (__bf16)f;
                bh[i] = h;
                bl[i] = (__bf16)(f - (float)h);
            }
            Bh[g][ks] = bh; Bl[g][ks] = bl;
        }
        {
            bf16x8 bh, bl;
            #pragma unroll
            for (int i = 0; i < 8; ++i){
                int k = e*32 + kgrp*8 + i;
                float f = kern[k*G3 + g*1024 + n*16 + arow];
                __bf16 h = (__bf16)f;
                bh[i] = h;
                bl[i] = (__bf16)(f - (float)h);
            }
            XBh[g] = bh; XBl[g] = bl;
        }
    }

    // combine-thread loop-invariant biases + publish index (plane 0)
    float cbz = 0.f, cbr = 0.f, cb0h = 0.f, cb1h = 0.f;
    size_t pubIdx = 0;
    if (tid < 256){
        int row = tid >> 4, j = tid & 15;
        int c = n*16 + j;
        cbz  = bias[c]        + bias[G3 + c];
        cbr  = bias[1024 + c] + bias[G3 + 1024 + c];
        cb0h = bias[2048 + c];
        cb1h = bias[G3 + 2048 + c];
        pubIdx = hfIdx(0, m, c, row);
    }

    // consumer fragment base (u64 units, plane 0): wave e, this lane
    const size_t cbase = (size_t)(((m*8 + e)*4)*64 + lane)*4;

    // ---- prologue: publish h(0) (tag 1), gather x(0) ----
    float hloc = 0.f;
    if (tid < 256){
        int row = tid >> 4, jj = tid & 15;
        int grow = m*16 + row, gcol = n*16 + jj;
        float hv = hid[grow*Hh + gcol];
        hloc = hv;
        __bf16 hb = (__bf16)hv;
        __bf16 lb = (__bf16)(hv - (float)hb);
        unsigned int val = (unsigned int)bfbits(hb)
                         | ((((unsigned int)bfbits(lb) & ~3u) | 1u) << 16);
        __hip_atomic_store(&hF[pubIdx], val, __ATOMIC_RELAXED, __HIP_MEMORY_SCOPE_AGENT);
    } else {
        gatherX256(&sX[0][0][0], &sX[0][1][0], inp, emb, m, 0, tid - 256);
    }
    __syncthreads();

    const int swz = (arow & 7) << 4;
    auto ldA = [&](const __bf16* base, int rowStrideB, int kbyte) -> bf16x8 {
        int off = (arow*rowStrideB + (kbyte ^ swz)) >> 1;
        return *(const bf16x8*)(base + off);
    };

    // ---- main sequential loop ----
    for (int t = 0; t < Tt; ++t){
        const int p = t & 1, qb = p ^ 1;
        const unsigned long long pat =
            (unsigned long long)((unsigned)(t + 1) & 3u) * 0x0001000000010000ULL;

        f32x4 acc0 = {0,0,0,0}, acc1 = {0,0,0,0};
        f32x4 acc2 = {0,0,0,0}, acc3 = {0,0,0,0};

        const unsigned long long* hb64 = (const unsigned long long*)hF;
        const size_t base = cbase + (size_t)p*PLANE_U64;

        // pass A: issue ALL 16 h-fragment loads first (fly under x-MFMAs)
        unsigned long long v[16];
        #pragma unroll
        for (int ks = 0; ks < 4; ++ks)
            #pragma unroll
            for (int j = 0; j < 4; ++j)
                v[ks*4 + j] = __hip_atomic_load(hb64 + base + ks*256 + j,
                                  __ATOMIC_RELAXED, __HIP_MEMORY_SCOPE_AGENT);

        // x-projection: LDS-resident, no dependency on the loads above
        {
            int kbx = e*64 + kgrp*16;               // byte offset in 512B row
            bf16x8 Ah = ldA(&sX[p][0][0], 512, kbx);
            bf16x8 Al = ldA(&sX[p][1][0], 512, kbx);
            acc0 = mfma16(Ah, XBh[0], acc0);
            acc1 = mfma16(Ah, XBh[1], acc1);
            acc3 = mfma16(Ah, XBh[2], acc3);
            acc0 = mfma16(Ah, XBl[0], acc0);
            acc1 = mfma16(Ah, XBl[1], acc1);
            acc3 = mfma16(Ah, XBl[2], acc3);
            acc0 = mfma16(Al, XBh[0], acc0);
            acc1 = mfma16(Al, XBh[1], acc1);
            acc3 = mfma16(Al, XBh[2], acc3);
        }

        // h(t) fragments: PIPELINED double-buffered self-validating retry.
        // Two passes always in flight, staggered by check/issue spacing —
        // detect quantum drops from one L3 RT to the stagger (~0.1us).
        {
            unsigned long long bad = 0;
            #pragma unroll
            for (int i = 0; i < 16; ++i)
                bad |= (v[i] ^ pat) & 0x0003000000030000ULL;
            if (!__all(bad == 0)){
                unsigned long long w[16];
                // issue pass B immediately (no wait on it yet)
                #pragma unroll
                for (int ks = 0; ks < 4; ++ks)
                    #pragma unroll
                    for (int j = 0; j < 4; ++j)
                        w[ks*4 + j] = __hip_atomic_load(hb64 + base + ks*256 + j,
                                          __ATOMIC_RELAXED, __HIP_MEMORY_SCOPE_AGENT);
                int spin = 0;
                bool inW = false;
                for (;;){
                    // re-issue pass A (flies during w's check)
                    #pragma unroll
                    for (int ks = 0; ks < 4; ++ks)
                        #pragma unroll
                        for (int j = 0; j < 4; ++j)
                            v[ks*4 + j] = __hip_atomic_load(hb64 + base + ks*256 + j,
                                              __ATOMIC_RELAXED, __HIP_MEMORY_SCOPE_AGENT);
                    // check pass B (its loads have been in flight the longest)
                    bad = 0;
                    #pragma unroll
                    for (int i = 0; i < 16; ++i)
                        bad |= (w[i] ^ pat) & 0x0003000000030000ULL;
                    if (__all(bad == 0)){ inW = true; break; }
                    // re-issue pass B (flies during v's check)
                    #pragma unroll
                    for (int ks = 0; ks < 4; ++ks)
                        #pragma unroll
                        for (int j = 0; j < 4; ++j)
                            w[ks*4 + j] = __hip_atomic_load(hb64 + base + ks*256 + j,
                                              __ATOMIC_RELAXED, __HIP_MEMORY_SCOPE_AGENT);
                    // check pass A
                    bad = 0;
                    #pragma unroll
                    for (int i = 0; i < 16; ++i)
                        bad |= (v[i] ^ pat) & 0x0003000000030000ULL;
                    if (__all(bad == 0)) break;        // v valid
                    if (++spin > 500000) break;        // safety valve
                }
                if (inW){
                    #pragma unroll
                    for (int i = 0; i < 16; ++i) v[i] = w[i];
                }
            }
        }
        // repack (hi|tagged-lo per u32 -> Ah/Al fragments) + h MFMAs
        #pragma unroll
        for (int ks = 0; ks < 4; ++ks){
            unsigned int ah[4], al[4];
            #pragma unroll
            for (int j = 0; j < 4; ++j){
                unsigned int a = (unsigned int)v[ks*4 + j];
                unsigned int b = (unsigned int)(v[ks*4 + j] >> 32);
                ah[j] = (a & 0xFFFFu) | (b << 16);
                al[j] = (a >> 16) | (b & 0xFFFF0000u);
            }
            bf16x8 Ah = __builtin_bit_cast(bf16x8, (u32x4){ah[0], ah[1], ah[2], ah[3]});
            bf16x8 Al = __builtin_bit_cast(bf16x8, (u32x4){al[0], al[1], al[2], al[3]});
            acc0 = mfma16(Ah, Bh[0][ks], acc0);
            acc1 = mfma16(Ah, Bh[1][ks], acc1);
            acc2 = mfma16(Ah, Bh[2][ks], acc2);
            acc0 = mfma16(Ah, Bl[0][ks], acc0);
            acc1 = mfma16(Ah, Bl[1][ks], acc1);
            acc2 = mfma16(Ah, Bl[2][ks], acc2);
            acc0 = mfma16(Al, Bh[0][ks], acc0);
            acc1 = mfma16(Al, Bh[1][ks], acc1);
            acc2 = mfma16(Al, Bh[2][ks], acc2);
        }
        #pragma unroll
        for (int r = 0; r < 4; ++r){
            int ix = (kgrp*4 + r)*16 + arow;        // C/D: row=(lane>>4)*4+r, col=lane&15
            sTile[e][0][ix] = acc0[r];
            sTile[e][1][ix] = acc1[r];
            sTile[e][2][ix] = acc2[r];
            sTile[e][3][ix] = acc3[r];
        }
        __syncthreads();   // B: all GEMM partials in sTile

        // combine + tagged publish (fire-and-forget, no drain, no flag)
        if (tid < 256){
            int row = tid >> 4, jj = tid & 15;
            int ix = row*16 + jj;
            float pz = cbz, pr = cbr, rh = cb1h, xh = cb0h;
            #pragma unroll
            for (int w = 0; w < 8; ++w){
                pz += sTile[w][0][ix];
                pr += sTile[w][1][ix];
                rh += sTile[w][2][ix];
                xh += sTile[w][3][ix];
            }
            // fast sigmoid/tanh via v_exp_f32 + v_rcp_f32 (r13 verbatim)
            const float LOG2E = 1.4426950408889634f;
            float z  = __builtin_amdgcn_rcpf(1.f + __builtin_amdgcn_exp2f(-pz*LOG2E));
            float r  = __builtin_amdgcn_rcpf(1.f + __builtin_amdgcn_exp2f(-pr*LOG2E));
            float a  = xh + r*rh;
            float hhat = 2.f*__builtin_amdgcn_rcpf(1.f + __builtin_amdgcn_exp2f(-2.f*LOG2E*a)) - 1.f;
            int grow = m*16 + row, gcol = n*16 + jj;
            float hn = z*hloc + (1.f - z)*hhat;
            hloc = hn;
            __bf16 nh = (__bf16)hn;
            __bf16 nl = (__bf16)(hn - (float)nh);
            unsigned int val = (unsigned int)bfbits(nh)
                | ((((unsigned int)bfbits(nl) & ~3u) | ((unsigned)(t + 2) & 3u)) << 16);
            __hip_atomic_store(&hF[pubIdx + (size_t)qb*PLANE_U32], val,
                               __ATOMIC_RELAXED, __HIP_MEMORY_SCOPE_AGENT);
            // out writes AFTER the publish: off the critical path
            out[((long)grow*Tt + t)*Hh + gcol] = hn;
            if (t == Tt - 1)
                out[(long)Bb*Tt*Hh + grow*Hh + gcol] = hn;  // final state
        } else {
            // gather x(t+1) on waves 4-7 (256 threads), concurrent with combine
            if (t + 1 < Tt)
                gatherX256(&sX[qb][0][0], &sX[qb][1][0], inp, emb, m, t + 1, tid - 256);
        }
        __syncthreads();   // E: sX(t+1) ready, sTile free for next GEMM
    }
}

extern "C" void kernel_launch(void* const* d_in, const int* in_sizes, int n_in,
                              void* d_out, int out_size, void* d_ws, size_t ws_size,
                              hipStream_t stream)
{
    (void)in_sizes; (void)n_in; (void)out_size; (void)ws_size;
    const int*   inp  = (const int*)  d_in[0];
    const float* hid  = (const float*)d_in[1];
    const float* emb  = (const float*)d_in[2];
    const float* kern = (const float*)d_in[3];
    const float* reck = (const float*)d_in[4];
    const float* bias = (const float*)d_in[5];
    float* out = (float*)d_out;
    unsigned char* ws = (unsigned char*)d_ws;

    // zero the exchange region: tag2=0 differs from every live tag on first use
    hipMemsetAsync(ws, 0, HF_BYTES, stream);

    void* args[] = {(void*)&inp, (void*)&hid, (void*)&emb, (void*)&kern,
                    (void*)&reck, (void*)&bias, (void*)&out, (void*)&ws};
    hipLaunchCooperativeKernel((void*)gru_persist, dim3(256), dim3(512),
                               args, 0, stream);
}

// Round 15
// 1883.332 us; speedup vs baseline: 1.2708x; 1.2708x over previous
//
#include <hip/hip_runtime.h>

#define Bb 64
#define Tt 512
#define Dd 256
#define Hh 1024
#define G3 3072

// workspace: self-validating h exchange, [2][4][8][4][64][8] u32 = 512 KB.
// u32 = hi16 | ((lo16 & ~3 | tag2) << 16); tag2 = (step+1)&3.
#define HF_BYTES (512*1024)
#define PLANE_U32 65536
#define PLANE_U64 32768

typedef __attribute__((ext_vector_type(8))) __bf16 bf16x8;
typedef __attribute__((ext_vector_type(4))) float f32x4;
typedef __attribute__((ext_vector_type(4))) unsigned int u32x4;

static __device__ __forceinline__ f32x4 mfma16(bf16x8 a, bf16x8 b, f32x4 c){
    return __builtin_amdgcn_mfma_f32_16x16x32_bf16(a, b, c, 0, 0, 0);
}
static __device__ __forceinline__ unsigned short bfbits(__bf16 v){
    return __builtin_bit_cast(unsigned short, v);
}

// u32 index of element (plane p, group m, col c, group-row row) in hF
static __device__ __forceinline__ size_t hfIdx(int p, int m, int c, int row){
    int e = c >> 7, ks = (c >> 5) & 3, kg = (c >> 3) & 3, i = c & 7;
    int lane = kg*16 + row;
    return (size_t)((((p*4 + m)*8 + e)*4 + ks)*64 + lane)*8 + i;
}

// gather embedding rows for timestep t into LDS x-buffer (hi/lo bf16 split),
// swizzled to match the MFMA A-fragment ds_read pattern. 256 threads
// (waves 4-7, lt 0..255), 4 chunks/thread. (r13 verbatim — verified passing)
__device__ __forceinline__ void gatherX256(__bf16* sxh, __bf16* sxl,
                                           const int* inp, const float* emb,
                                           int m, int t, int lt)
{
    int row = lt >> 4, c16 = lt & 15;
    int grow = m*16 + row;
    int tok = inp[grow*Tt + t];
    const float* er = emb + (long)tok * Dd;
    int swz = (row & 7) << 4;
    #pragma unroll
    for (int qq = 0; qq < 4; ++qq){
        int c = c16 + qq*16;                     // 4-float chunk, 0..63
        float4 v = *(const float4*)(er + c*4);
        int boff = row*512 + ((c*8) ^ swz);      // byte offset, 8B-aligned
        float vv[4] = {v.x, v.y, v.z, v.w};
        unsigned long long Hp = 0, Lp = 0;
        #pragma unroll
        for (int ee = 0; ee < 4; ++ee){
            __bf16 hb = (__bf16)vv[ee];
            __bf16 lb = (__bf16)(vv[ee] - (float)hb);
            Hp |= (unsigned long long)bfbits(hb) << (16*ee);
            Lp |= (unsigned long long)bfbits(lb) << (16*ee);
        }
        *(unsigned long long*)((char*)sxh + boff) = Hp;
        *(unsigned long long*)((char*)sxl + boff) = Lp;
    }
}

extern "C" __global__ void __launch_bounds__(512, 2)
gru_persist(const int* __restrict__ inp, const float* __restrict__ hid,
            const float* __restrict__ emb, const float* __restrict__ kern,
            const float* __restrict__ reck, const float* __restrict__ bias,
            float* __restrict__ out, unsigned char* __restrict__ ws)
{
    __shared__ __bf16 sX[2][2][16*256];  // [buf][hi/lo], 32 KB total (r2 layout)
    __shared__ float  sTile[8][4][256];  // [kwave][z,r,hrec,hx][row*16+col], 32 KB

    const int tid  = threadIdx.x;
    const int wid  = tid >> 6;
    const int lane = tid & 63;
    const int blk  = blockIdx.x;
    const int m = blk & 3;       // row group: rows 16m..16m+15
    const int n = blk >> 2;      // j group:  j = 16n..16n+15

    unsigned int* hF = (unsigned int*)ws;

    const int e    = wid;               // K-eighth owned by this wave (0..7)
    const int kgrp = lane >> 4;         // 0..3 (k sub-block)
    const int arow = lane & 15;         // A row / B col within tile

    // ---- one-time weight fragments in VGPRs (hi/lo bf16 split, r5 verbatim) ----
    bf16x8 Bh[3][4], Bl[3][4], XBh[3], XBl[3];
    #pragma unroll
    for (int g = 0; g < 3; ++g){
        #pragma unroll
        for (int ks = 0; ks < 4; ++ks){
            bf16x8 bh, bl;
            #pragma unroll
            for (int i = 0; i < 8; ++i){
                int k = e*128 + ks*32 + kgrp*8 + i;
                float f = reck[k*G3 + g*1024 + n*16 + arow];
                __bf16 h = (__bf16)f;
                bh[i] = h;
                bl[i] = (__bf16)(f - (float)h);
            }
            Bh[g][ks] = bh; Bl[g][ks] = bl;
        }
        {
            bf16x8 bh, bl;
            #pragma unroll
            for (int i = 0; i < 8; ++i){
                int k = e*32 + kgrp*8 + i;
                float f = kern[k*G3 + g*1024 + n*16 + arow];
                __bf16 h = (__bf16)f;
                bh[i] = h;
                bl[i] = (__bf16)(f - (float)h);
            }
            XBh[g] = bh; XBl[g] = bl;
        }
    }

    // combine-thread loop-invariant biases + publish index (plane 0)
    float cbz = 0.f, cbr = 0.f, cb0h = 0.f, cb1h = 0.f;
    size_t pubIdx = 0;
    if (tid < 256){
        int row = tid >> 4, j = tid & 15;
        int c = n*16 + j;
        cbz  = bias[c]        + bias[G3 + c];
        cbr  = bias[1024 + c] + bias[G3 + 1024 + c];
        cb0h = bias[2048 + c];
        cb1h = bias[G3 + 2048 + c];
        pubIdx = hfIdx(0, m, c, row);
    }

    // consumer fragment base (u64 units, plane 0): wave e, this lane
    const size_t cbase = (size_t)(((m*8 + e)*4)*64 + lane)*4;

    // ---- prologue: publish h(0) (tag 1), gather x(0) ----
    float hloc = 0.f;
    if (tid < 256){
        int row = tid >> 4, jj = tid & 15;
        int grow = m*16 + row, gcol = n*16 + jj;
        float hv = hid[grow*Hh + gcol];
        hloc = hv;
        __bf16 hb = (__bf16)hv;
        __bf16 lb = (__bf16)(hv - (float)hb);
        unsigned int val = (unsigned int)bfbits(hb)
                         | ((((unsigned int)bfbits(lb) & ~3u) | 1u) << 16);
        __hip_atomic_store(&hF[pubIdx], val, __ATOMIC_RELAXED, __HIP_MEMORY_SCOPE_AGENT);
    } else {
        gatherX256(&sX[0][0][0], &sX[0][1][0], inp, emb, m, 0, tid - 256);
    }
    __syncthreads();

    const int swz = (arow & 7) << 4;
    auto ldA = [&](const __bf16* base, int rowStrideB, int kbyte) -> bf16x8 {
        int off = (arow*rowStrideB + (kbyte ^ swz)) >> 1;
        return *(const bf16x8*)(base + off);
    };

    // ---- main sequential loop ----
    for (int t = 0; t < Tt; ++t){
        const int p = t & 1, qb = p ^ 1;
        const unsigned long long pat =
            (unsigned long long)((unsigned)(t + 1) & 3u) * 0x0001000000010000ULL;

        f32x4 acc0 = {0,0,0,0}, acc1 = {0,0,0,0};
        f32x4 acc2 = {0,0,0,0}, acc3 = {0,0,0,0};

        const unsigned long long* hb64 = (const unsigned long long*)hF;
        const size_t base = cbase + (size_t)p*PLANE_U64;

        // pass-0: issue ALL 16 h-fragment loads first (fly under x-MFMAs)
        unsigned long long v[16];
        #pragma unroll
        for (int ks = 0; ks < 4; ++ks)
            #pragma unroll
            for (int j = 0; j < 4; ++j)
                v[ks*4 + j] = __hip_atomic_load(hb64 + base + ks*256 + j,
                                  __ATOMIC_RELAXED, __HIP_MEMORY_SCOPE_AGENT);

        // x-projection: LDS-resident, no dependency on the loads above
        {
            int kbx = e*64 + kgrp*16;               // byte offset in 512B row
            bf16x8 Ah = ldA(&sX[p][0][0], 512, kbx);
            bf16x8 Al = ldA(&sX[p][1][0], 512, kbx);
            acc0 = mfma16(Ah, XBh[0], acc0);
            acc1 = mfma16(Ah, XBh[1], acc1);
            acc3 = mfma16(Ah, XBh[2], acc3);
            acc0 = mfma16(Ah, XBl[0], acc0);
            acc1 = mfma16(Ah, XBl[1], acc1);
            acc3 = mfma16(Ah, XBl[2], acc3);
            acc0 = mfma16(Al, XBh[0], acc0);
            acc1 = mfma16(Al, XBh[1], acc1);
            acc3 = mfma16(Al, XBh[2], acc3);
        }

        // h(t) fragments: 16 self-validating u64 loads, retry until all
        // 32 embedded tags match. ONE L3 round trip in steady state.
        {
            int spin = 0;
            for (;;){
                unsigned long long bad = 0;
                #pragma unroll
                for (int i = 0; i < 16; ++i)
                    bad |= (v[i] ^ pat) & 0x0003000000030000ULL;
                if (__all(bad == 0)) break;
                if (++spin > 1000000) break;   // safety valve: wrong, not wedged
                #pragma unroll
                for (int ks = 0; ks < 4; ++ks)
                    #pragma unroll
                    for (int j = 0; j < 4; ++j)
                        v[ks*4 + j] = __hip_atomic_load(hb64 + base + ks*256 + j,
                                          __ATOMIC_RELAXED, __HIP_MEMORY_SCOPE_AGENT);
            }
        }
        // repack (hi|tagged-lo per u32 -> Ah/Al fragments) + h MFMAs
        #pragma unroll
        for (int ks = 0; ks < 4; ++ks){
            unsigned int ah[4], al[4];
            #pragma unroll
            for (int j = 0; j < 4; ++j){
                unsigned int a = (unsigned int)v[ks*4 + j];
                unsigned int b = (unsigned int)(v[ks*4 + j] >> 32);
                ah[j] = (a & 0xFFFFu) | (b << 16);
                al[j] = (a >> 16) | (b & 0xFFFF0000u);
            }
            bf16x8 Ah = __builtin_bit_cast(bf16x8, (u32x4){ah[0], ah[1], ah[2], ah[3]});
            bf16x8 Al = __builtin_bit_cast(bf16x8, (u32x4){al[0], al[1], al[2], al[3]});
            acc0 = mfma16(Ah, Bh[0][ks], acc0);
            acc1 = mfma16(Ah, Bh[1][ks], acc1);
            acc2 = mfma16(Ah, Bh[2][ks], acc2);
            acc0 = mfma16(Ah, Bl[0][ks], acc0);
            acc1 = mfma16(Ah, Bl[1][ks], acc1);
            acc2 = mfma16(Ah, Bl[2][ks], acc2);
            acc0 = mfma16(Al, Bh[0][ks], acc0);
            acc1 = mfma16(Al, Bh[1][ks], acc1);
            acc2 = mfma16(Al, Bh[2][ks], acc2);
        }
        #pragma unroll
        for (int r = 0; r < 4; ++r){
            int ix = (kgrp*4 + r)*16 + arow;        // C/D: row=(lane>>4)*4+r, col=lane&15
            sTile[e][0][ix] = acc0[r];
            sTile[e][1][ix] = acc1[r];
            sTile[e][2][ix] = acc2[r];
            sTile[e][3][ix] = acc3[r];
        }
        __syncthreads();   // B: all GEMM partials in sTile

        // combine + tagged publish (fire-and-forget, no drain, no flag)
        if (tid < 256){
            int row = tid >> 4, jj = tid & 15;
            int ix = row*16 + jj;
            float pz = cbz, pr = cbr, rh = cb1h, xh = cb0h;
            #pragma unroll
            for (int w = 0; w < 8; ++w){
                pz += sTile[w][0][ix];
                pr += sTile[w][1][ix];
                rh += sTile[w][2][ix];
                xh += sTile[w][3][ix];
            }
            // fast sigmoid/tanh via v_exp_f32 + v_rcp_f32 (saturates correctly;
            // ~1 ulp/op, well inside the 7x error margin)
            const float LOG2E = 1.4426950408889634f;
            float z  = __builtin_amdgcn_rcpf(1.f + __builtin_amdgcn_exp2f(-pz*LOG2E));
            float r  = __builtin_amdgcn_rcpf(1.f + __builtin_amdgcn_exp2f(-pr*LOG2E));
            float a  = xh + r*rh;
            float hhat = 2.f*__builtin_amdgcn_rcpf(1.f + __builtin_amdgcn_exp2f(-2.f*LOG2E*a)) - 1.f;
            int grow = m*16 + row, gcol = n*16 + jj;
            float hn = z*hloc + (1.f - z)*hhat;
            hloc = hn;
            __bf16 nh = (__bf16)hn;
            __bf16 nl = (__bf16)(hn - (float)nh);
            unsigned int val = (unsigned int)bfbits(nh)
                | ((((unsigned int)bfbits(nl) & ~3u) | ((unsigned)(t + 2) & 3u)) << 16);
            __hip_atomic_store(&hF[pubIdx + (size_t)qb*PLANE_U32], val,
                               __ATOMIC_RELAXED, __HIP_MEMORY_SCOPE_AGENT);
            // out writes AFTER the publish: off the critical path
            out[((long)grow*Tt + t)*Hh + gcol] = hn;
            if (t == Tt - 1)
                out[(long)Bb*Tt*Hh + grow*Hh + gcol] = hn;  // final state
        } else {
            // gather x(t+1) on ALL of waves 4-7 (256 threads), concurrent with
            // the combine waves — halves the chain that was gating barrier E.
            if (t + 1 < Tt)
                gatherX256(&sX[qb][0][0], &sX[qb][1][0], inp, emb, m, t + 1, tid - 256);
        }
        __syncthreads();   // E: sX(t+1) ready, sTile free for next GEMM
    }
}

extern "C" void kernel_launch(void* const* d_in, const int* in_sizes, int n_in,
                              void* d_out, int out_size, void* d_ws, size_t ws_size,
                              hipStream_t stream)
{
    (void)in_sizes; (void)n_in; (void)out_size; (void)ws_size;
    const int*   inp  = (const int*)  d_in[0];
    const float* hid  = (const float*)d_in[1];
    const float* emb  = (const float*)d_in[2];
    const float* kern = (const float*)d_in[3];
    const float* reck = (const float*)d_in[4];
    const float* bias = (const float*)d_in[5];
    float* out = (float*)d_out;
    unsigned char* ws = (unsigned char*)d_ws;

    // zero the exchange region: tag2=0 differs from every live tag on first use
    hipMemsetAsync(ws, 0, HF_BYTES, stream);

    void* args[] = {(void*)&inp, (void*)&hid, (void*)&emb, (void*)&kern,
                    (void*)&reck, (void*)&bias, (void*)&out, (void*)&ws};
    hipLaunchCooperativeKernel((void*)gru_persist, dim3(256), dim3(512),
                               args, 0, stream);
}